// Round 1
// 383.867 us; speedup vs baseline: 1.0082x; 1.0082x over previous
//
#include <hip/hip_runtime.h>
#include <hip/hip_bf16.h>

// B=4, N=2048, DIMX=384, DIMQ=48, H=8.
// out_b = sum_h softmax(Q K^T/sqrt(48)) @ U_bh,  U_bh = X_b M_h^T,  M_h = W_rh W_vh.
// ws layout (bytes), with Xw/Wqw/Wkw aliased INSIDE Ow (dead until attn runs):
//   Mw  bf16 [h*384+c][k:384]          @ 0           (2,359,296)
//   Qw  bf16 [bh][i:2048][d:64 pad]    @ 2,359,296   (8,388,608)
//   Kw  bf16 same                      @ 10,747,904  (8,388,608)
//   UT  bf16 [bh][c:384][j:2048]       @ 19,136,512  (50,331,648)
//   Ow  bf16 [bh][i:2048][c:384]       @ 69,468,160  (50,331,648)
//     Xw  bf16 [b][j:2048][k:384]      @ 69,468,160  (6,291,456)   } alias Ow
//     Wqw bf16 [384][384]              @ 75,759,616  (294,912)     }
//     Wkw bf16 [384][384]              @ 76,054,528  (294,912)     }
// peak = 119,799,808 B

typedef short bf16x8 __attribute__((ext_vector_type(8)));
typedef float f32x4 __attribute__((ext_vector_type(4)));
typedef unsigned short ushort_t;
typedef unsigned int uint_t;

#define MFMA16(A, B, C) __builtin_amdgcn_mfma_f32_16x16x32_bf16(A, B, C, 0, 0, 0)

__device__ __forceinline__ ushort_t bits_bf16(float a) {
  __hip_bfloat16 h = __float2bfloat16(a);
  return *reinterpret_cast<ushort_t*>(&h);
}

// ---------- fp32 -> bf16 convert ----------
__global__ __launch_bounds__(256) void cvt_kernel(const float* __restrict__ src,
                                                  ushort_t* __restrict__ dst, int n4) {
  const int idx = blockIdx.x * 256 + threadIdx.x;
  if (idx >= n4) return;
  const float4 v = ((const float4*)src)[idx];
  ushort4 o;
  o.x = bits_bf16(v.x); o.y = bits_bf16(v.y); o.z = bits_bf16(v.z); o.w = bits_bf16(v.w);
  ((ushort4*)dst)[idx] = o;
}

// ---------- M_h = W_rh * W_vh  (fp32 compute, bf16 out; tiny) ----------
__global__ __launch_bounds__(256) void prep_m_kernel(const float* __restrict__ Wr,
                                                     const float* __restrict__ Wv,
                                                     ushort_t* __restrict__ Mw) {
  __shared__ float As[32][68];
  __shared__ float Bs[32][68];
  const int t = threadIdx.x;
  const int d0 = blockIdx.x << 6;
  const int k0 = blockIdx.y << 6;
  const int h  = blockIdx.z;
  const int ty = t >> 4, tx = t & 15;
  float acc[4][4] = {};
  for (int x0 = 0; x0 < 384; x0 += 32) {
#pragma unroll
    for (int rep = 0; rep < 2; ++rep) {
      int idx = t + (rep << 8);
      int row = idx >> 3, kq = (idx & 7) << 2;
      const float4 a = *(const float4*)&Wr[(size_t)(d0 + row) * 3072 + h * 384 + x0 + kq];
      As[kq + 0][row] = a.x; As[kq + 1][row] = a.y; As[kq + 2][row] = a.z; As[kq + 3][row] = a.w;
      int bro = idx >> 4, bc4 = (idx & 15) << 2;
      *(float4*)&Bs[bro][bc4] = *(const float4*)&Wv[(size_t)(h * 384 + x0 + bro) * 384 + k0 + bc4];
    }
    __syncthreads();
#pragma unroll
    for (int kk = 0; kk < 32; ++kk) {
      const float4 av = *(const float4*)&As[kk][ty << 2];
      const float4 bv = *(const float4*)&Bs[kk][tx << 2];
      const float a[4] = {av.x, av.y, av.z, av.w};
      const float b[4] = {bv.x, bv.y, bv.z, bv.w};
#pragma unroll
      for (int r = 0; r < 4; ++r)
#pragma unroll
        for (int c = 0; c < 4; ++c) acc[r][c] = fmaf(a[r], b[c], acc[r][c]);
    }
    __syncthreads();
  }
#pragma unroll
  for (int r = 0; r < 4; ++r)
#pragma unroll
    for (int c = 0; c < 4; ++c)
      Mw[(size_t)(h * 384 + d0 + (ty << 2) + r) * 384 + k0 + (tx << 2) + c] =
          bits_bf16(acc[r][c]);
}

// ---------- unified bf16 MFMA GEMM (unchanged) ----------
template <int MODE>
__global__ __launch_bounds__(256) void gemm_kernel(const ushort_t* __restrict__ Aall,
                                                   const ushort_t* __restrict__ Ball,
                                                   ushort_t* __restrict__ dst) {
  __shared__ ushort_t As[128 * 40];
  __shared__ ushort_t Bs[128 * 40];
  const int t = threadIdx.x;
  const int w = t >> 6, lane = t & 63, quad = lane >> 4, l16 = lane & 15;
  const int m0 = blockIdx.x << 7;
  const int n0 = blockIdx.y << 7;
  const ushort_t* Ap;
  const ushort_t* Bp;
  if (MODE == 0) {
    Ap = Aall; Bp = Ball;
  } else {
    const int bh = blockIdx.z, h = bh & 7, b = bh >> 3;
    Ap = Aall + (size_t)h * 384 * 384;
    Bp = Ball + (size_t)b * 2048 * 384;
  }
  const int wm = (w & 1) << 6, wn = (w >> 1) << 6;
  f32x4 acc[4][4] = {};

  for (int k0 = 0; k0 < 384; k0 += 32) {
    __syncthreads();
#pragma unroll
    for (int rep = 0; rep < 2; ++rep) {
      const int idx = t + (rep << 8);
      const int row = idx >> 2, c8 = (idx & 3) << 3;
      *(bf16x8*)&As[row * 40 + c8] = *(const bf16x8*)&Ap[(size_t)(m0 + row) * 384 + k0 + c8];
      *(bf16x8*)&Bs[row * 40 + c8] = *(const bf16x8*)&Bp[(size_t)(n0 + row) * 384 + k0 + c8];
    }
    __syncthreads();
    bf16x8 af[4], bfr[4];
#pragma unroll
    for (int x = 0; x < 4; ++x) {
      af[x] = *(const bf16x8*)&As[(wm + x * 16 + l16) * 40 + quad * 8];
      bfr[x] = *(const bf16x8*)&Bs[(wn + x * 16 + l16) * 40 + quad * 8];
    }
#pragma unroll
    for (int ti = 0; ti < 4; ++ti)
#pragma unroll
      for (int tj = 0; tj < 4; ++tj)
        acc[ti][tj] = MFMA16(af[ti], bfr[tj], acc[ti][tj]);
  }

#pragma unroll
  for (int ti = 0; ti < 4; ++ti) {
    const int gm0 = m0 + wm + ti * 16 + quad * 4;
#pragma unroll
    for (int tj = 0; tj < 4; ++tj) {
      const int gn = n0 + wn + tj * 16 + l16;
#pragma unroll
      for (int r = 0; r < 4; ++r) {
        const ushort_t v = bits_bf16(acc[ti][tj][r]);
        if (MODE == 0) {
          const int m = gm0 + r, b = m >> 11, i = m & 2047;
          const int h = gn / 48, dd = gn - h * 48;
          dst[(size_t)(((b << 3) + h) * 2048 + i) * 64 + dd] = v;
        } else {
          dst[((size_t)blockIdx.z * 384 + gm0 + r) * 2048 + gn] = v;
        }
      }
    }
  }
}

// ---------- fused attention via MFMA, round-5 pipeline ----------
// T4 applied: raw s_barrier with lgkm-only drain (vmem stays in flight across the
// barrier), U tile loaded ONE jt ahead, issues staggered inside the PV tc-loop so
// register peak grows only ~16 VGPRs (cur[tc] dies as next[tc] is born).
// Each U load gets a full jt (~2K cyc) of flight instead of ~450 before vmcnt(0).
__global__ __launch_bounds__(256, 2) void attn_pv_kernel(const ushort_t* __restrict__ Qw,
                                                         const ushort_t* __restrict__ Kw,
                                                         const ushort_t* __restrict__ UT,
                                                         __hip_bfloat16* __restrict__ Ow) {
  __shared__ uint_t Ps[2][64 * 44];
  __shared__ float Lw[4][64];
  __shared__ float Ls[64];

  const int t = threadIdx.x;
  const int w = t >> 6, lane = t & 63, quad = lane >> 4, l16 = lane & 15;
  const int bid = blockIdx.x;
  const int h = bid & 7, i0 = ((bid >> 3) & 31) << 6, b = bid >> 8;
  const int bh = (b << 3) + h;

  const ushort_t* Qg = Qw + ((size_t)bh * 2048 + i0 + l16) * 64 + quad * 8;
  const ushort_t* Kg = Kw + ((size_t)bh * 2048 + w * 16 + l16) * 64 + quad * 8;
  const ushort_t* Ug = UT + ((size_t)bh * 384 + w * 96 + l16) * 2048 + quad * 8;

  bf16x8 qf[4][2];
#pragma unroll
  for (int ti = 0; ti < 4; ++ti)
#pragma unroll
    for (int kh = 0; kh < 2; ++kh)
      qf[ti][kh] = *(const bf16x8*)(Qg + (size_t)ti * 16 * 64 + kh * 32);

  f32x4 acc[4][6] = {};
  float lp[4] = {0.f, 0.f, 0.f, 0.f};
  // exp(s/sqrt(48)) = exp2(s * log2(e)/sqrt(48))
  const float c_exp = 0.14433756729740643f * 1.4426950408889634f;

  // prologue: K tile 0 and U tile 0 into registers
  bf16x8 kf0 = *(const bf16x8*)(Kg);
  bf16x8 kf1 = *(const bf16x8*)(Kg + 32);
  bf16x8 uf[2][6][2];
#pragma unroll
  for (int tc = 0; tc < 6; ++tc) {
    const ushort_t* up = Ug + (size_t)tc * 16 * 2048;
    uf[0][tc][0] = *(const bf16x8*)(up);
    uf[0][tc][1] = *(const bf16x8*)(up + 32);
  }

#define ATTN_STEP(JT, CUR, NXT)                                                        \
  {                                                                                    \
    const int jn = (((JT) + 1) & 31) << 6;                                             \
    /* ---- scores: S^T tile, wave w owns j-strip w*16..+15 ---- */                    \
    f32x4 sv[4];                                                                       \
    _Pragma("unroll") for (int ti = 0; ti < 4; ++ti) {                                 \
      f32x4 z = {0.f, 0.f, 0.f, 0.f};                                                  \
      z = MFMA16(kf0, qf[ti][0], z);                                                   \
      z = MFMA16(kf1, qf[ti][1], z);                                                   \
      sv[ti] = z;                                                                      \
    }                                                                                  \
    /* ---- prefetch next K tile (waited by dataflow next iter) ---- */                \
    bf16x8 kn0 = *(const bf16x8*)(Kg + (size_t)jn * 64);                               \
    bf16x8 kn1 = *(const bf16x8*)(Kg + (size_t)jn * 64 + 32);                          \
    /* ---- exp via exp2 + round-to-bf16 (bits+0x8000) + v_perm pack ---- */           \
    uint_t pw[4][2];                                                                   \
    _Pragma("unroll") for (int ti = 0; ti < 4; ++ti) {                                 \
      const uint_t r0 = __float_as_uint(exp2f(sv[ti][0] * c_exp)) + 0x8000u;           \
      const uint_t r1 = __float_as_uint(exp2f(sv[ti][1] * c_exp)) + 0x8000u;           \
      const uint_t r2 = __float_as_uint(exp2f(sv[ti][2] * c_exp)) + 0x8000u;           \
      const uint_t r3 = __float_as_uint(exp2f(sv[ti][3] * c_exp)) + 0x8000u;           \
      const uint_t p0 = __builtin_amdgcn_perm(r1, r0, 0x07060302u);                    \
      const uint_t p1 = __builtin_amdgcn_perm(r3, r2, 0x07060302u);                    \
      pw[ti][0] = p0;                                                                  \
      pw[ti][1] = p1;                                                                  \
      lp[ti] += (__uint_as_float(p0 << 16) + __uint_as_float(p0 & 0xffff0000u)) +      \
                (__uint_as_float(p1 << 16) + __uint_as_float(p1 & 0xffff0000u));       \
    }                                                                                  \
    /* ---- write Ps[CUR] (b64, 2-way max banks at stride 44) ---- */                  \
    {                                                                                  \
      uint2* p = (uint2*)&Ps[CUR][w * 8 + quad * 2];                                   \
      _Pragma("unroll") for (int ti = 0; ti < 4; ++ti)                                 \
          *(uint2*)((uint_t*)p + (ti * 16 + l16) * 44) = uint2{pw[ti][0], pw[ti][1]};  \
    }                                                                                  \
    /* ---- raw barrier: drain LDS only, vmem loads stay in flight ---- */             \
    __builtin_amdgcn_sched_barrier(0);                                                 \
    asm volatile("s_waitcnt lgkmcnt(0)");                                              \
    __builtin_amdgcn_s_barrier();                                                      \
    __builtin_amdgcn_sched_barrier(0);                                                 \
    /* ---- P A-fragments: ds_read_b128, 2-way banks ---- */                           \
    bf16x8 pA[4][2];                                                                   \
    _Pragma("unroll") for (int ti = 0; ti < 4; ++ti)                                   \
        _Pragma("unroll") for (int ks = 0; ks < 2; ++ks)                               \
            pA[ti][ks] =                                                               \
                *(const bf16x8*)&Ps[CUR][(ti * 16 + l16) * 44 + ks * 16 + quad * 4];   \
    /* ---- PV on register-resident U; stagger next-U issue per tc ---- */             \
    _Pragma("unroll") for (int tc = 0; tc < 6; ++tc) {                                 \
      _Pragma("unroll") for (int ti = 0; ti < 4; ++ti)                                 \
          acc[ti][tc] = MFMA16(pA[ti][0], uf[CUR][tc][0], acc[ti][tc]);                \
      _Pragma("unroll") for (int ti = 0; ti < 4; ++ti)                                 \
          acc[ti][tc] = MFMA16(pA[ti][1], uf[CUR][tc][1], acc[ti][tc]);                \
      const ushort_t* up_ = Ug + (size_t)tc * 16 * 2048 + jn;                          \
      uf[NXT][tc][0] = *(const bf16x8*)(up_);                                          \
      uf[NXT][tc][1] = *(const bf16x8*)(up_ + 32);                                     \
    }                                                                                  \
    kf0 = kn0;                                                                         \
    kf1 = kn1;                                                                         \
  }

  for (int jt = 0; jt < 32; jt += 2) {
    ATTN_STEP(jt, 0, 1)
    ATTN_STEP(jt + 1, 1, 0)
  }
#undef ATTN_STEP

  // ---- softmax denominators ----
#pragma unroll
  for (int ti = 0; ti < 4; ++ti) {
    lp[ti] += __shfl_xor(lp[ti], 16);
    lp[ti] += __shfl_xor(lp[ti], 32);
  }
  if (lane < 16) {
#pragma unroll
    for (int ti = 0; ti < 4; ++ti) Lw[w][ti * 16 + lane] = lp[ti];
  }
  __syncthreads();
  if (t < 64) Ls[t] = 1.0f / (Lw[0][t] + Lw[1][t] + Lw[2][t] + Lw[3][t]);
  __syncthreads();

  // ---- epilogue: normalize, store bf16 partial O ----
  __hip_bfloat16* Op = Ow + ((size_t)bh * 2048 + i0) * 384 + w * 96 + l16;
#pragma unroll
  for (int ti = 0; ti < 4; ++ti)
#pragma unroll
    for (int r = 0; r < 4; ++r) {
      const float inv = Ls[ti * 16 + quad * 4 + r];
      __hip_bfloat16* op = Op + (size_t)(ti * 16 + quad * 4 + r) * 384;
#pragma unroll
      for (int tc = 0; tc < 6; ++tc) op[tc * 16] = __float2bfloat16(acc[ti][tc][r] * inv);
    }
}

// ---------- reduce 8 heads ----------
__global__ __launch_bounds__(256) void reduce_kernel(const uint_t* __restrict__ OwU,
                                                     float2* __restrict__ out) {
  const int idx = blockIdx.x * 256 + threadIdx.x;
  const int b = idx / 393216;
  const int rem = idx - b * 393216;
  const uint_t* p = OwU + (size_t)b * 8 * 393216 + rem;
  float s0 = 0.f, s1 = 0.f;
#pragma unroll
  for (int h = 0; h < 8; ++h) {
    const uint_t v = p[(size_t)h * 393216];
    s0 += __uint_as_float(v << 16);
    s1 += __uint_as_float(v & 0xffff0000u);
  }
  out[(size_t)b * 393216 + rem] = float2{s0, s1};
}

extern "C" void kernel_launch(void* const* d_in, const int* in_sizes, int n_in,
                              void* d_out, int out_size, void* d_ws, size_t ws_size,
                              hipStream_t stream) {
  const float* X  = (const float*)d_in[0];
  const float* Wq = (const float*)d_in[1];
  const float* Wk = (const float*)d_in[2];
  const float* Wv = (const float*)d_in[3];
  const float* Wr = (const float*)d_in[4];

  char* ws = (char*)d_ws;
  ushort_t* Mw  = (ushort_t*)(ws);
  ushort_t* Qw  = (ushort_t*)(ws + 2359296);
  ushort_t* Kw  = (ushort_t*)(ws + 10747904);
  ushort_t* UT  = (ushort_t*)(ws + 19136512);
  __hip_bfloat16* Ow = (__hip_bfloat16*)(ws + 69468160);
  ushort_t* Xw  = (ushort_t*)(ws + 69468160);   // aliases Ow (dead until attn)
  ushort_t* Wqw = (ushort_t*)(ws + 75759616);   // aliases Ow
  ushort_t* Wkw = (ushort_t*)(ws + 76054528);   // aliases Ow

  hipMemsetAsync(ws + 2359296, 0, 16777216, stream);  // dq 48->64 pad of Q/K

  cvt_kernel<<<dim3(3072), 256, 0, stream>>>(X, Xw, 786432);
  cvt_kernel<<<dim3(144), 256, 0, stream>>>(Wq, Wqw, 36864);
  cvt_kernel<<<dim3(144), 256, 0, stream>>>(Wk, Wkw, 36864);
  prep_m_kernel<<<dim3(6, 6, 8), 256, 0, stream>>>(Wr, Wv, Mw);

  gemm_kernel<0><<<dim3(64, 3), 256, 0, stream>>>(Xw, Wqw, Qw);
  gemm_kernel<0><<<dim3(64, 3), 256, 0, stream>>>(Xw, Wkw, Kw);
  gemm_kernel<1><<<dim3(3, 16, 32), 256, 0, stream>>>(Mw, Xw, UT);

  attn_pv_kernel<<<dim3(1024), 256, 0, stream>>>(Qw, Kw, UT, Ow);
  reduce_kernel<<<dim3(6144), 256, 0, stream>>>((const uint_t*)Ow, (float2*)d_out);
}